// Round 1
// baseline (72.181 us; speedup 1.0000x reference)
//
#include <hip/hip_runtime.h>

// ---------------------------------------------------------------------------
// Fused MLP-embedding cosine-similarity kernel for MI355X (gfx950).
//
//   e1 = MLP(s1), e2 = MLP(s2)  (128 ->256 selu-> 256 selu-> 128)
//   out = sigmoid((cos(e1,e2)+1)/2)
//
// Strategy: bf16 MFMA (16x16x32), weights pre-packed to B-fragment order in
// d_ws by a tiny pre-kernel; one block = 32 pairs = 64 MLP rows; activations
// ping-pong through XOR-swizzled LDS; col-partitioned waves keep W-fragments
// in registers across row stripes.
// ---------------------------------------------------------------------------

typedef __bf16 bf16x8 __attribute__((ext_vector_type(8)));
typedef float  f32x4  __attribute__((ext_vector_type(4)));

constexpr int NPAIR_TILE = 32;   // pairs per block
// d_ws layout (bf16 elements): W-fragments in ((ct*KS+ks)*64+lane)*8+j order
constexpr int WS_W1 = 0;         // 16 ct * 4 ks * 512 = 32768
constexpr int WS_W2 = 32768;     // 16 ct * 8 ks * 512 = 65536
constexpr int WS_W3 = 98304;     //  8 ct * 8 ks * 512 = 32768
// total 131072 bf16 = 256 KiB of d_ws

__device__ __forceinline__ float selu_f(float x) {
    const float scale = 1.0507009873554805f;
    const float sa    = 1.7580993408473766f;   // scale * alpha
    float xp = fmaxf(x, 0.f);
    float xn = fminf(x, 0.f);
    return fmaf(scale, xp, sa * (__expf(xn) - 1.f));
}

// --- pre-kernel: convert fp32 weights to bf16 in MFMA B-fragment order -----
// B-frag layout for v_mfma_f32_16x16x32_bf16: lane l holds
//   B[k = ks*32 + (l>>4)*8 + j][col = ct*16 + (l&15)],  j = 0..7
// W is row-major [out][in], so col = out-neuron, k = in index.
__global__ void pack_weights_kernel(const float* __restrict__ W1,
                                    const float* __restrict__ W2,
                                    const float* __restrict__ W3,
                                    __bf16* __restrict__ ws) {
    int t = blockIdx.x * blockDim.x + threadIdx.x;      // 0..16383
    const float* W; int K, KS, f, base;
    if (t < 4096)       { W = W1; K = 128; KS = 4; f = t;         base = WS_W1; }
    else if (t < 12288) { W = W2; K = 256; KS = 8; f = t - 4096;  base = WS_W2; }
    else                { W = W3; K = 256; KS = 8; f = t - 12288; base = WS_W3; }
    int lane = f & 63;
    int ks   = (f >> 6) % KS;
    int ct   = f / (64 * KS);
    int col  = ct * 16 + (lane & 15);
    int k0   = ks * 32 + (lane >> 4) * 8;
    const float* src = W + (size_t)col * K + k0;
    __bf16* dst = ws + base + (size_t)f * 8;
#pragma unroll
    for (int j = 0; j < 8; ++j) dst[j] = (__bf16)src[j];
}

// --- one MLP layer on a 64-row tile ----------------------------------------
// in_lds : bf16 [64][IN_COLS], XOR-swizzled (byte ^= (row&7)<<4)
// out_lds: bf16 [64][OUT_COLS], same swizzle
// wave owns NCT col-tiles of 16 neurons; B-frags held in VGPRs across stripes.
template<int KS, int NCT, int IN_COLS, int OUT_COLS, bool DO_SELU>
__device__ __forceinline__ void mlp_layer(const __bf16* in_lds, __bf16* out_lds,
                                          const __bf16* __restrict__ wf,
                                          const float* __restrict__ bias,
                                          int wave, int lane) {
    bf16x8 bfr[NCT][KS];
#pragma unroll
    for (int c = 0; c < NCT; ++c)
#pragma unroll
        for (int ks = 0; ks < KS; ++ks)
            bfr[c][ks] = *(const bf16x8*)(wf + (size_t)(((wave * NCT + c) * KS + ks) * 64 + lane) * 8);

    float bv[NCT];
#pragma unroll
    for (int c = 0; c < NCT; ++c)
        bv[c] = bias[(wave * NCT + c) * 16 + (lane & 15)];

    const int lr = lane & 15;        // A-row / C-col within tile
    const int kg = lane >> 4;        // k-group

#pragma unroll
    for (int s = 0; s < 4; ++s) {    // 4 row-stripes of 16
        const int arow = s * 16 + lr;
        bf16x8 af[KS];
#pragma unroll
        for (int ks = 0; ks < KS; ++ks) {
            unsigned byte = (unsigned)((arow * IN_COLS + ks * 32 + kg * 8) * 2) ^ ((arow & 7) << 4);
            af[ks] = *(const bf16x8*)((const char*)in_lds + byte);
        }
#pragma unroll
        for (int c = 0; c < NCT; ++c) {
            f32x4 acc = { bv[c], bv[c], bv[c], bv[c] };
#pragma unroll
            for (int ks = 0; ks < KS; ++ks)
                acc = __builtin_amdgcn_mfma_f32_16x16x32_bf16(af[ks], bfr[c][ks], acc, 0, 0, 0);
            const int col = (wave * NCT + c) * 16 + lr;
#pragma unroll
            for (int j = 0; j < 4; ++j) {
                float v = acc[j];
                if (DO_SELU) v = selu_f(v);
                const int orow = s * 16 + kg * 4 + j;   // C/D: row = 4*(lane>>4)+j
                unsigned byte = (unsigned)((orow * OUT_COLS + col) * 2) ^ ((orow & 7) << 4);
                *(__bf16*)((char*)out_lds + byte) = (__bf16)v;
            }
        }
    }
}

// --- main fused kernel ------------------------------------------------------
__global__ __launch_bounds__(256, 2)
void embed_sim_kernel(const float* __restrict__ s1, const float* __restrict__ s2,
                      const float* __restrict__ b1, const float* __restrict__ b2,
                      const float* __restrict__ b3,
                      const __bf16* __restrict__ wf, float* __restrict__ out) {
    __shared__ __align__(16) __bf16 Xs[64 * 128];   // 16 KB; reused for E after layer 3
    __shared__ __align__(16) __bf16 H1[64 * 256];   // 32 KB
    __shared__ __align__(16) __bf16 H2[64 * 256];   // 32 KB   (total 80 KB -> 2 blocks/CU)

    const int tid  = threadIdx.x;
    const int wave = tid >> 6;
    const int lane = tid & 63;
    const int p0   = blockIdx.x * NPAIR_TILE;

    // ---- stage X: rows 0..31 = s1[p0..], rows 32..63 = s2[p0..] ----
#pragma unroll
    for (int it = 0; it < 4; ++it) {
        int idx = tid + it * 256;            // 0..1023 chunks of 8 floats
        int row = idx >> 4;
        int k0  = (idx & 15) << 3;
        const float* src = (row < 32) ? (s1 + (size_t)(p0 + row) * 128 + k0)
                                      : (s2 + (size_t)(p0 + row - 32) * 128 + k0);
        float4 v0 = *(const float4*)(src);
        float4 v1 = *(const float4*)(src + 4);
        bf16x8 w;
        w[0] = (__bf16)v0.x; w[1] = (__bf16)v0.y; w[2] = (__bf16)v0.z; w[3] = (__bf16)v0.w;
        w[4] = (__bf16)v1.x; w[5] = (__bf16)v1.y; w[6] = (__bf16)v1.z; w[7] = (__bf16)v1.w;
        unsigned byte = (unsigned)((row * 128 + k0) * 2) ^ ((row & 7) << 4);
        *(bf16x8*)((char*)Xs + byte) = w;
    }
    __syncthreads();

    mlp_layer<4, 4, 128, 256, true >(Xs, H1, wf + WS_W1, b1, wave, lane);
    __syncthreads();
    mlp_layer<8, 4, 256, 256, true >(H1, H2, wf + WS_W2, b2, wave, lane);
    __syncthreads();
    mlp_layer<8, 2, 256, 128, false>(H2, Xs, wf + WS_W3, b3, wave, lane);   // E -> Xs
    __syncthreads();

    // ---- epilogue: per pair p, dot/norms over 128 dims (8 threads/pair) ----
    const int p  = tid >> 3;
    const int dg = tid & 7;
    float dot = 0.f, n1 = 0.f, n2 = 0.f;
#pragma unroll
    for (int half = 0; half < 2; ++half) {
        int d0 = dg * 16 + half * 8;
        unsigned by1 = (unsigned)((p * 128 + d0) * 2) ^ ((p & 7) << 4);
        unsigned by2 = (unsigned)(((p + 32) * 128 + d0) * 2) ^ (((p + 32) & 7) << 4);
        bf16x8 e1 = *(const bf16x8*)((const char*)Xs + by1);
        bf16x8 e2 = *(const bf16x8*)((const char*)Xs + by2);
#pragma unroll
        for (int j = 0; j < 8; ++j) {
            float a = (float)e1[j], b = (float)e2[j];
            dot = fmaf(a, b, dot);
            n1  = fmaf(a, a, n1);
            n2  = fmaf(b, b, n2);
        }
    }
#pragma unroll
    for (int off = 1; off < 8; off <<= 1) {
        dot += __shfl_xor(dot, off);
        n1  += __shfl_xor(n1,  off);
        n2  += __shfl_xor(n2,  off);
    }
    if (dg == 0) {
        float r = dot * rsqrtf(n1 * n2);
        float x = (r + 1.f) * 0.5f;
        out[p0 + p] = 1.f / (1.f + __expf(-x));
    }
}

// ---------------------------------------------------------------------------
extern "C" void kernel_launch(void* const* d_in, const int* in_sizes, int n_in,
                              void* d_out, int out_size, void* d_ws, size_t ws_size,
                              hipStream_t stream) {
    const float* s1 = (const float*)d_in[0];
    const float* s2 = (const float*)d_in[1];
    const float* W1 = (const float*)d_in[2];
    const float* b1 = (const float*)d_in[3];
    const float* W2 = (const float*)d_in[4];
    const float* b2 = (const float*)d_in[5];
    const float* W3 = (const float*)d_in[6];
    const float* b3 = (const float*)d_in[7];
    __bf16* wf = (__bf16*)d_ws;                 // needs 256 KiB of d_ws
    float*  outp = (float*)d_out;

    pack_weights_kernel<<<64, 256, 0, stream>>>(W1, W2, W3, wf);

    const int npairs = in_sizes[0] / 128;       // 65536
    embed_sim_kernel<<<npairs / NPAIR_TILE, 256, 0, stream>>>(s1, s2, b1, b2, b3, wf, outp);
}